// Round 1
// baseline (66.138 us; speedup 1.0000x reference)
//
#include <hip/hip_runtime.h>
#include <math.h>

// RefractiveInterface: per-ray Ferrari quartic solve (fp64, matching the JAX
// reference's complex128 path), geometry + error selection in fp32.

__device__ __forceinline__ void cbrt_c(double re, double im, double& ore, double& oim) {
    // principal complex cube root: |z|^(1/3) * cis(atan2(im,re)/3)
    double rho = sqrt(re * re + im * im);
    double m = cbrt(rho);
    double th = atan2(im, re) * (1.0 / 3.0);
    double s, c;
    sincos(th, &s, &c);
    ore = m * c;
    oim = m * s;
}

__global__ __launch_bounds__(256) void refract_kernel(
    const float* __restrict__ pos,
    const float* __restrict__ nrm,
    const float* __restrict__ dpt,
    float* __restrict__ out,
    int N)
{
    int i = blockIdx.x * blockDim.x + threadIdx.x;
    if (i >= N) return;

    const float mu = 1.33f;
    float n0 = nrm[0], n1 = nrm[1];
    float d_eff = fmaxf(dpt[0], 0.0f) + 0.001f;   // relu(d)/1.0 + 0.001

    // z1 = nvec / ||nvec||, normal = -z1   (all fp32 like reference)
    float nn = sqrtf(n0 * n0 + n1 * n1 + 1.0f);
    float z1x = n0 / nn, z1y = n1 / nn, z1z = 1.0f / nn;
    float ax = -z1x, ay = -z1y, az = -z1z;        // normal

    float px = pos[3 * i + 0], py = pos[3 * i + 1], pz = pos[3 * i + 2];

    // por = cross(normal, pos); normalize
    float porx = ay * pz - az * py;
    float pory = az * px - ax * pz;
    float porz = ax * py - ay * px;
    float pn = sqrtf(porx * porx + pory * pory + porz * porz);
    porx /= pn; pory /= pn; porz /= pn;

    // z2 = cross(por, z1)
    float z2x = pory * z1z - porz * z1y;
    float z2y = porz * z1x - porx * z1z;
    float z2z = porx * z1y - pory * z1x;

    float v = px * z1x + py * z1y + pz * z1z;
    float u = px * z2x + py * z2y + pz * z2z;

    // quartic coefficients computed in fp32 (reference casts to f64 AFTER)
    float c1f = (mu - 1.0f) * (mu + 1.0f);
    float c2f = -2.0f * u * (mu - 1.0f) * (mu + 1.0f);
    float c3f = d_eff * d_eff * mu * mu - d_eff * d_eff + 2.0f * d_eff * v
              + mu * mu * u * u - u * u - v * v;
    float c4f = -2.0f * d_eff * d_eff * mu * mu * u;
    float c5f = d_eff * d_eff * mu * mu * u * u;

    // ---- fp64 Ferrari ----
    double A0 = (double)c5f / (double)c1f;
    double A1 = (double)c4f / (double)c1f;
    double A2 = (double)c3f / (double)c1f;
    double A3 = (double)c2f / (double)c1f;

    double p = A2 - 6.0 * A3 * A3 / 16.0;
    double h = A3 / 4.0;
    double q = A1 - A2 * A3 / 2.0 + 8.0 * (h * h * h);
    double r = A0 - A1 * A3 / 4.0 + A2 * A3 * A3 / 16.0 - 3.0 * ((h * h) * (h * h));

    // resolvent cubic: x^3 + (2p) x^2 + (p^2 - 4r) x - q^2
    double B2 = 2.0 * p;
    double B1 = p * p - 4.0 * r;
    double B0 = -(q * q);
    double pc = B1 - B2 * B2 / 3.0;
    double qc = B0 - B1 * B2 / 3.0 + B2 * B2 * B2 * 2.0 / 27.0;
    double Dc = (qc / 2.0) * (qc / 2.0) + (pc / 3.0) * (pc / 3.0) * (pc / 3.0) + 1e-12;

    double rcr, rci;
    if (Dc >= 0.0) { rcr = sqrt(Dc); rci = 0.0; }
    else           { rcr = 0.0;      rci = sqrt(-Dc); }

    double mql = -qc / 2.0;
    double Lre, Lim, Rre, Rim;
    cbrt_c(mql + rcr,  rci, Lre, Lim);   // (-q/2 + r)^(1/3)
    cbrt_c(mql - rcr, -rci, Rre, Rim);   // (-q/2 - r)^(1/3); -0.0 imag -> theta=-pi branch, matches numpy

    const double o_re = -0.5;
    const double o_im = 0.8660254037844386;         // sqrt(3)/2
    const double o2_re = o_re * o_re - o_im * o_im; // o*o (python complex-mult rounding)
    const double o2_im = 2.0 * o_re * o_im;

    double sh = B2 / 3.0;
    double u0r = Lre + Rre - sh;
    double u0i = Lim + Rim;
    double u1r = (o2_re * Lre - o2_im * Lim) + (o_re * Rre - o_im * Rim) - sh;
    double u1i = (o2_re * Lim + o2_im * Lre) + (o_re * Rim + o_im * Rre);
    double u2r = (o_re * Lre - o_im * Lim) + (o2_re * Rre - o2_im * Rim) - sh;
    double u2i = (o_re * Lim + o_im * Lre) + (o2_re * Rim + o2_im * Rre);

    // cost = where(real<0, 1e6, |imag|); first-occurrence argmin
    double cost0 = (u0r < 0.0) ? 1e6 : fabs(u0i);
    double cost1 = (u1r < 0.0) ? 1e6 : fabs(u1i);
    double cost2 = (u2r < 0.0) ? 1e6 : fabs(u2i);
    double t = u0r; double cb = cost0;
    if (cost1 < cb) { cb = cost1; t = u1r; }
    if (cost2 < cb) { cb = cost2; t = u2r; }
    t = fmax(t, 1e-6);
    double st = sqrt(t);

    double cq1 = (p + t) / 2.0 - st * q / (2.0 * t);
    double cq2 = (p + t) / 2.0 + st * q / (2.0 * t);
    double D1 = st * st - 4.0 * cq1;
    double D2 = st * st - 4.0 * cq2;
    double s1r, s1i, s2r, s2i;
    if (D1 >= 0.0) { s1r = sqrt(D1); s1i = 0.0; } else { s1r = 0.0; s1i = sqrt(-D1); }
    if (D2 >= 0.0) { s2r = sqrt(D2); s2i = 0.0; } else { s2r = 0.0; s2i = sqrt(-D2); }

    // roots = y - A3/4, cast to complex64 (fp32)
    float xr[4], xi[4];
    xr[0] = (float)((-st + s1r) / 2.0 - h);  xi[0] = (float)(s1i / 2.0);
    xr[1] = (float)((-st - s1r) / 2.0 - h);  xi[1] = (float)((-s1i) / 2.0);
    xr[2] = (float)(( st + s2r) / 2.0 - h);  xi[2] = (float)(s2i / 2.0);
    xr[3] = (float)(( st - s2r) / 2.0 - h);  xi[3] = (float)((-s2i) / 2.0);

    // ---- fp32 error metric & root selection ----
    float bb = -d_eff;                 // vi . n2 with n2=[0,-1]
    float mm = 1.0f - mu * mu;
    float invmu = 1.0f / mu;
    float errv[4];
    #pragma unroll
    for (int k = 0; k < 4; ++k) {
        float x = xr[k];
        float bbb = x * x + d_eff * d_eff;
        float bq = (-bb - sqrtf(bb * bb - mm * bbb)) / mu;
        float vrx = invmu * x;
        float vry = invmu * d_eff - bq;
        float e = fabsf((u - x) * vry - (v - d_eff) * vrx);
        if (fabsf(xi[k]) > 0.001f) e = INFINITY;
        errv[k] = e;
    }
    int bi = 0; float eb = errv[0];
    if (errv[1] < eb) { eb = errv[1]; bi = 1; }
    if (errv[2] < eb) { eb = errv[2]; bi = 2; }
    if (errv[3] < eb) { eb = errv[3]; bi = 3; }
    float best = xr[bi];

    out[3 * i + 0] = best * z2x + d_eff * z1x;
    out[3 * i + 1] = best * z2y + d_eff * z1y;
    out[3 * i + 2] = best * z2z + d_eff * z1z;
}

extern "C" void kernel_launch(void* const* d_in, const int* in_sizes, int n_in,
                              void* d_out, int out_size, void* d_ws, size_t ws_size,
                              hipStream_t stream) {
    const float* pos = (const float*)d_in[0];
    const float* nrm = (const float*)d_in[1];
    const float* dpt = (const float*)d_in[2];
    float* out = (float*)d_out;
    int N = in_sizes[0] / 3;
    int block = 256;
    int grid = (N + block - 1) / block;
    refract_kernel<<<grid, block, 0, stream>>>(pos, nrm, dpt, out, N);
}

// Round 2
// 49.427 us; speedup vs baseline: 1.3381x; 1.3381x over previous
//
#include <hip/hip_runtime.h>
#include <math.h>

// RefractiveInterface: per-ray Ferrari quartic solve.
// fp64 skeleton matching the JAX complex128 reference, but the heavy fp64
// transcendentals (atan2/sincos/cbrt) are replaced by:
//   Dc>=0: real cbrt (cbrtf seed + fp64 Newton) + constant cis(pi/3) rotation
//   Dc<0 : fp32 atan2f/sincosf seed, then 2x fp64 Newton polish of the
//          selected resolvent root on the monic cubic.

__device__ __forceinline__ double cbrt_nr(double x) {
    // cube root of x >= 0: fp32 seed + one fp64 Newton step (~1e-13 rel)
    double y = (double)cbrtf((float)x);
    double y2 = y * y;
    if (y2 > 0.0) y = 0.6666666666666666 * y + 0.3333333333333333 * (x / y2);
    return y;
}

__global__ __launch_bounds__(256) void refract_kernel(
    const float* __restrict__ pos,
    const float* __restrict__ nrm,
    const float* __restrict__ dpt,
    float* __restrict__ out,
    int N)
{
    int i = blockIdx.x * blockDim.x + threadIdx.x;
    if (i >= N) return;

    const float mu = 1.33f;
    float n0 = nrm[0], n1 = nrm[1];
    float d_eff = fmaxf(dpt[0], 0.0f) + 0.001f;   // relu(d)/1.0 + 0.001

    // ---- fp32 geometry (matches reference dtype path) ----
    float nn = sqrtf(n0 * n0 + n1 * n1 + 1.0f);
    float z1x = n0 / nn, z1y = n1 / nn, z1z = 1.0f / nn;
    float ax = -z1x, ay = -z1y, az = -z1z;        // normal

    float px = pos[3 * i + 0], py = pos[3 * i + 1], pz = pos[3 * i + 2];

    float porx = ay * pz - az * py;
    float pory = az * px - ax * pz;
    float porz = ax * py - ay * px;
    float pn = sqrtf(porx * porx + pory * pory + porz * porz);
    porx /= pn; pory /= pn; porz /= pn;

    float z2x = pory * z1z - porz * z1y;
    float z2y = porz * z1x - porx * z1z;
    float z2z = porx * z1y - pory * z1x;

    float v = px * z1x + py * z1y + pz * z1z;
    float u = px * z2x + py * z2y + pz * z2z;

    // quartic coefficients in fp32 (reference casts to f64 AFTER stacking)
    float c2f = -2.0f * u * (mu - 1.0f) * (mu + 1.0f);
    float c3f = d_eff * d_eff * mu * mu - d_eff * d_eff + 2.0f * d_eff * v
              + mu * mu * u * u - u * u - v * v;
    float c4f = -2.0f * d_eff * d_eff * mu * mu * u;
    float c5f = d_eff * d_eff * mu * mu * u * u;

    // ---- fp64 Ferrari ----
    const double invc1 = 1.0 / (double)((1.33f - 1.0f) * (1.33f + 1.0f));
    double A0 = (double)c5f * invc1;
    double A1 = (double)c4f * invc1;
    double A2 = (double)c3f * invc1;
    double A3 = (double)c2f * invc1;

    double h = A3 * 0.25;
    double p = A2 - (6.0 * A3) * A3 * 0.0625;
    double q = A1 - A2 * A3 * 0.5 + 8.0 * ((h * h) * h);
    double r = A0 - A1 * A3 * 0.25 + ((A2 * A3) * A3) * 0.0625
             - 3.0 * ((h * h) * (h * h));

    // resolvent cubic: t^3 + B2 t^2 + B1 t + B0
    double B2 = 2.0 * p;
    double B1 = p * p - 4.0 * r;
    double B0 = -(q * q);
    double pc = B1 - B2 * B2 * (1.0 / 3.0);
    double qc = B0 - B1 * B2 * (1.0 / 3.0) + ((B2 * B2) * B2) * (2.0 / 27.0);
    double half_qc = qc * 0.5;
    double pc3 = pc * (1.0 / 3.0);
    double Dc = half_qc * half_qc + (pc3 * pc3) * pc3 + 1e-12;

    double mql = -half_qc;
    double sh = B2 * (1.0 / 3.0);

    const double C_IM = 0.8660254037844386;        // sqrt(3)/2
    double Lre, Lim, Rre, Rim;

    if (Dc >= 0.0) {
        // one real cubic root; cube-root args real, imag(+0.0) semantics:
        // negative arg -> principal branch rotation by +pi/3 (for BOTH L and R)
        double rcr = sqrt(Dc);
        double a = mql + rcr;
        double b = mql - rcr;
        double ca = cbrt_nr(fabs(a));
        double cb = cbrt_nr(fabs(b));
        if (a >= 0.0) { Lre = ca;       Lim = 0.0;        }
        else          { Lre = 0.5 * ca; Lim = C_IM * ca;  }
        if (b >= 0.0) { Rre = cb;       Rim = 0.0;        }
        else          { Rre = 0.5 * cb; Rim = C_IM * cb;  }
    } else {
        // casus irreducibilis: R = conj(L); one fp32 angle, polish later
        double rci = sqrt(-Dc);
        double rho = sqrt(mql * mql - Dc);         // |mql + i*rci|
        double m = cbrt_nr(rho);
        float th = atan2f((float)rci, (float)mql) * (1.0f / 3.0f);
        float sf, cf;
        sincosf(th, &sf, &cf);
        Lre = m * (double)cf;
        Lim = m * (double)sf;
        Rre = Lre;
        Rim = -Lim;
    }

    // omega combinations (omega = cis(2pi/3), o2 = o*o with python rounding)
    const double o_re = -0.5;
    const double o_im = C_IM;
    const double o2_re = o_re * o_re - o_im * o_im;
    const double o2_im = 2.0 * o_re * o_im;

    double u0r = Lre + Rre - sh;
    double u0i = Lim + Rim;
    double u1r = (o2_re * Lre - o2_im * Lim) + (o_re * Rre - o_im * Rim) - sh;
    double u1i = (o2_re * Lim + o2_im * Lre) + (o_re * Rim + o_im * Rre);
    double u2r = (o_re * Lre - o_im * Lim) + (o2_re * Rre - o2_im * Rim) - sh;
    double u2i = (o_re * Lim + o_im * Lre) + (o2_re * Rim + o2_im * Rre);

    // cost = where(real<0, 1e6, |imag|); first-occurrence argmin
    double cost0 = (u0r < 0.0) ? 1e6 : fabs(u0i);
    double cost1 = (u1r < 0.0) ? 1e6 : fabs(u1i);
    double cost2 = (u2r < 0.0) ? 1e6 : fabs(u2i);
    double t = u0r; double cb_ = cost0;
    if (cost1 < cb_) { cb_ = cost1; t = u1r; }
    if (cost2 < cb_) { cb_ = cost2; t = u2r; }

    if (Dc < 0.0) {
        // selected t is a genuine real root of the resolvent: Newton-polish
        // in fp64 to restore ~1e-13 agreement with the reference's complex128
        #pragma unroll
        for (int it = 0; it < 2; ++it) {
            double f  = ((t + B2) * t + B1) * t + B0;
            double fp = (3.0 * t + 2.0 * B2) * t + B1;
            double dt = f / fp;
            if (isfinite(dt) && fabs(dt) < 0.1 * fabs(t) + 1e-2) t -= dt;
        }
    }

    t = fmax(t, 1e-6);
    double st = sqrt(t);

    double w = st * q / (2.0 * t);
    double pt2 = (p + t) * 0.5;
    double cq1 = pt2 - w;
    double cq2 = pt2 + w;
    double D1 = st * st - 4.0 * cq1;
    double D2 = st * st - 4.0 * cq2;
    double s1r, s1i, s2r, s2i;
    if (D1 >= 0.0) { s1r = sqrt(D1); s1i = 0.0; } else { s1r = 0.0; s1i = sqrt(-D1); }
    if (D2 >= 0.0) { s2r = sqrt(D2); s2i = 0.0; } else { s2r = 0.0; s2i = sqrt(-D2); }

    // roots = y - A3/4, cast to complex64 (fp32)
    float xr[4], xi[4];
    xr[0] = (float)((-st + s1r) * 0.5 - h);  xi[0] = (float)(s1i * 0.5);
    xr[1] = (float)((-st - s1r) * 0.5 - h);  xi[1] = (float)(-s1i * 0.5);
    xr[2] = (float)(( st + s2r) * 0.5 - h);  xi[2] = (float)(s2i * 0.5);
    xr[3] = (float)(( st - s2r) * 0.5 - h);  xi[3] = (float)(-s2i * 0.5);

    // ---- fp32 error metric & root selection ----
    float bb = -d_eff;                 // vi . n2 with n2=[0,-1]
    float mm = 1.0f - mu * mu;
    float invmu = 1.0f / mu;
    float errv[4];
    #pragma unroll
    for (int k = 0; k < 4; ++k) {
        float x = xr[k];
        float bbb = x * x + d_eff * d_eff;
        float bq = (-bb - sqrtf(bb * bb - mm * bbb)) / mu;
        float vrx = invmu * x;
        float vry = invmu * d_eff - bq;
        float e = fabsf((u - x) * vry - (v - d_eff) * vrx);
        if (fabsf(xi[k]) > 0.001f) e = INFINITY;
        errv[k] = e;
    }
    int bi = 0; float eb = errv[0];
    if (errv[1] < eb) { eb = errv[1]; bi = 1; }
    if (errv[2] < eb) { eb = errv[2]; bi = 2; }
    if (errv[3] < eb) { eb = errv[3]; bi = 3; }
    float best = xr[bi];

    out[3 * i + 0] = best * z2x + d_eff * z1x;
    out[3 * i + 1] = best * z2y + d_eff * z1y;
    out[3 * i + 2] = best * z2z + d_eff * z1z;
}

extern "C" void kernel_launch(void* const* d_in, const int* in_sizes, int n_in,
                              void* d_out, int out_size, void* d_ws, size_t ws_size,
                              hipStream_t stream) {
    const float* pos = (const float*)d_in[0];
    const float* nrm = (const float*)d_in[1];
    const float* dpt = (const float*)d_in[2];
    float* out = (float*)d_out;
    int N = in_sizes[0] / 3;
    int block = 256;
    int grid = (N + block - 1) / block;
    refract_kernel<<<grid, block, 0, stream>>>(pos, nrm, dpt, out, N);
}

// Round 3
// 36.582 us; speedup vs baseline: 1.8080x; 1.3511x over previous
//
#include <hip/hip_runtime.h>
#include <math.h>

// RefractiveInterface: per-ray Ferrari quartic solve replicating the JAX
// complex128 reference. Key algebraic fact (derived symbolically from the
// coefficient structure): the resolvent's depressed-cubic p-coefficient is
// pc = -A2^2/3 <= 0 always, so:
//   Dc<0      : 3 genuine real roots -> any non-negative one is
//               factorization-equivalent -> largest root via fp32 trig seed
//               + one fp64 Halley step.
//   Dc>=0,a,b>=0: single genuine real root -> fp32 cbrt seed + Halley.
//   else (junk): the reference's principal-branch Cardano fabricates
//               non-roots; replicate exactly in fp64 (refined cbrts + omega
//               combos + cost argmin), no polish possible.

__global__ __launch_bounds__(256) void refract_kernel(
    const float* __restrict__ pos,
    const float* __restrict__ nrm,
    const float* __restrict__ dpt,
    float* __restrict__ out,
    int N)
{
    int i = blockIdx.x * blockDim.x + threadIdx.x;
    if (i >= N) return;

    const float mu = 1.33f;
    float n0 = nrm[0], n1 = nrm[1];
    float d_eff = fmaxf(dpt[0], 0.0f) + 0.001f;   // relu(d)/1.0 + 0.001

    // ---- fp32 geometry (matches reference dtype path) ----
    float nn = sqrtf(n0 * n0 + n1 * n1 + 1.0f);
    float z1x = n0 / nn, z1y = n1 / nn, z1z = 1.0f / nn;
    float ax = -z1x, ay = -z1y, az = -z1z;        // normal

    float px = pos[3 * i + 0], py = pos[3 * i + 1], pz = pos[3 * i + 2];

    float porx = ay * pz - az * py;
    float pory = az * px - ax * pz;
    float porz = ax * py - ay * px;
    float pn = sqrtf(porx * porx + pory * pory + porz * porz);
    porx /= pn; pory /= pn; porz /= pn;

    float z2x = pory * z1z - porz * z1y;
    float z2y = porz * z1x - porx * z1z;
    float z2z = porx * z1y - pory * z1x;

    float v = px * z1x + py * z1y + pz * z1z;
    float u = px * z2x + py * z2y + pz * z2z;

    // quartic coefficients in fp32 (reference casts to f64 AFTER stacking)
    float c2f = -2.0f * u * (mu - 1.0f) * (mu + 1.0f);
    float c3f = d_eff * d_eff * mu * mu - d_eff * d_eff + 2.0f * d_eff * v
              + mu * mu * u * u - u * u - v * v;
    float c4f = -2.0f * d_eff * d_eff * mu * mu * u;
    float c5f = d_eff * d_eff * mu * mu * u * u;

    // ---- fp64 coefficient chain (same op structure as reference) ----
    const double invc1 = 1.0 / (double)((1.33f - 1.0f) * (1.33f + 1.0f));
    double A0 = (double)c5f * invc1;
    double A1 = (double)c4f * invc1;
    double A2 = (double)c3f * invc1;
    double A3 = (double)c2f * invc1;

    double h = A3 * 0.25;
    double p = A2 - (6.0 * A3) * A3 * 0.0625;
    double q = A1 - A2 * A3 * 0.5 + 8.0 * ((h * h) * h);
    double r = A0 - A1 * A3 * 0.25 + ((A2 * A3) * A3) * 0.0625
             - 3.0 * ((h * h) * (h * h));

    double B2 = 2.0 * p;
    double B1 = p * p - 4.0 * r;
    double B0 = -(q * q);
    double pc  = B1 - B2 * B2 * (1.0 / 3.0);
    double qc  = B0 - B1 * B2 * (1.0 / 3.0) + ((B2 * B2) * B2) * (2.0 / 27.0);
    double hq  = qc * 0.5;
    double pc3 = pc * (1.0 / 3.0);
    double Dc  = hq * hq + (pc3 * pc3) * pc3 + 1e-12;
    double mql = -hq;
    double sh  = B2 * (1.0 / 3.0);

    double t;
    bool polish;

    if (Dc < 0.0) {
        // 3 genuine real roots: take the largest (trig form, fp32 seed)
        float rr  = sqrtf((float)(-pc3));          // sqrt(-pc/3) > 1e-2 here
        float rho = rr * rr * rr;
        float cphi = fminf(fmaxf((float)mql / rho, -1.0f), 1.0f);
        float yy = 2.0f * rr * cosf(acosf(cphi) * (1.0f / 3.0f));
        t = (double)yy - sh;
        polish = true;
    } else {
        double rcr = sqrt(Dc);
        double aa = mql + rcr;
        double bb = mql - rcr;
        if (aa >= 0.0 && bb >= 0.0) {
            // genuine single real root: fp32 cbrt seeds + Halley
            t = (double)(cbrtf((float)aa) + cbrtf((float)bb)) - sh;
            polish = true;
        } else {
            // reference-junk replication (principal-branch Cardano)
            double xa = fabs(aa), xb = fabs(bb);
            double ya = (double)cbrtf((float)xa);
            double yb = (double)cbrtf((float)xb);
            if (ya > 0.0) ya = (2.0 * ya + xa / (ya * ya)) * (1.0 / 3.0);
            if (yb > 0.0) yb = (2.0 * yb + xb / (yb * yb)) * (1.0 / 3.0);
            const double CI = 0.8660254037844386;  // sqrt(3)/2
            double Lre, Lim, Rre, Rim;
            if (aa >= 0.0) { Lre = ya;       Lim = 0.0;     }
            else           { Lre = 0.5 * ya; Lim = CI * ya; }
            if (bb >= 0.0) { Rre = yb;       Rim = 0.0;     }
            else           { Rre = 0.5 * yb; Rim = CI * yb; }
            const double o_re = -0.5, o_im = CI;
            const double o2_re = o_re * o_re - o_im * o_im;
            const double o2_im = 2.0 * o_re * o_im;
            double u0r = Lre + Rre - sh;
            double u0i = Lim + Rim;
            double u1r = (o2_re * Lre - o2_im * Lim) + (o_re * Rre - o_im * Rim) - sh;
            double u1i = (o2_re * Lim + o2_im * Lre) + (o_re * Rim + o_im * Rre);
            double u2r = (o_re * Lre - o_im * Lim) + (o2_re * Rre - o2_im * Rim) - sh;
            double u2i = (o_re * Lim + o_im * Lre) + (o2_re * Rim + o2_im * Rre);
            double cost0 = (u0r < 0.0) ? 1e6 : fabs(u0i);
            double cost1 = (u1r < 0.0) ? 1e6 : fabs(u1i);
            double cost2 = (u2r < 0.0) ? 1e6 : fabs(u2i);
            t = u0r; double cbv = cost0;
            if (cost1 < cbv) { cbv = cost1; t = u1r; }
            if (cost2 < cbv) { cbv = cost2; t = u2r; }
            polish = false;
        }
    }

    if (polish) {
        // one Halley step on f(t) = t^3 + B2 t^2 + B1 t + B0 (seed ~1e-7 rel)
        double f   = ((t + B2) * t + B1) * t + B0;
        double fp  = (3.0 * t + 2.0 * B2) * t + B1;
        double fpp = 6.0 * t + 2.0 * B2;
        double den = fp * fp - 0.5 * f * fpp;
        double dt  = f * fp / den;
        if (isfinite(dt) && fabs(dt) < 0.1 * fabs(t) + 1e-2) t -= dt;
    }

    t = fmax(t, 1e-6);
    double rs = rsqrt(t);          // fp64 rsqrt: replaces sqrt + div
    double st = t * rs;
    double w  = (q * rs) * 0.5;    // == st*q/(2t)
    double pt2 = (p + t) * 0.5;
    double cq1 = pt2 - w;
    double cq2 = pt2 + w;
    double stst = st * st;
    double D1 = stst - 4.0 * cq1;
    double D2 = stst - 4.0 * cq2;

    // sqrt values in fp32 (sign decisions stay fp64); |imag|<=5e-4 in any
    // sign-flip window, below the 0.001 threshold -> classification safe
    float s1r, s1i, s2r, s2i;
    if (D1 >= 0.0) { s1r = sqrtf((float)D1); s1i = 0.0f; }
    else           { s1r = 0.0f; s1i = sqrtf((float)(-D1)); }
    if (D2 >= 0.0) { s2r = sqrtf((float)D2); s2i = 0.0f; }
    else           { s2r = 0.0f; s2i = sqrtf((float)(-D2)); }

    float stf = (float)st;
    float hf  = (float)h;
    float xr[4], xi[4];
    xr[0] = (-stf + s1r) * 0.5f - hf;  xi[0] = s1i * 0.5f;
    xr[1] = (-stf - s1r) * 0.5f - hf;  xi[1] = s1i * 0.5f;
    xr[2] = ( stf + s2r) * 0.5f - hf;  xi[2] = s2i * 0.5f;
    xr[3] = ( stf - s2r) * 0.5f - hf;  xi[3] = s2i * 0.5f;

    // ---- fp32 error metric & root selection ----
    float invmu = 1.0f / mu;
    float mm = 1.0f - mu * mu;
    float de2 = d_eff * d_eff;
    float vd  = v - d_eff;
    float errv[4];
    #pragma unroll
    for (int k = 0; k < 4; ++k) {
        float x = xr[k];
        float bbb = x * x + de2;
        float bq = (d_eff - sqrtf(de2 - mm * bbb)) * invmu;
        float vrx = invmu * x;
        float vry = invmu * d_eff - bq;
        float e = fabsf((u - x) * vry - vd * vrx);
        if (fabsf(xi[k]) > 0.001f) e = INFINITY;
        errv[k] = e;
    }
    int bi = 0; float eb = errv[0];
    if (errv[1] < eb) { eb = errv[1]; bi = 1; }
    if (errv[2] < eb) { eb = errv[2]; bi = 2; }
    if (errv[3] < eb) { eb = errv[3]; bi = 3; }
    float best = xr[bi];

    out[3 * i + 0] = best * z2x + d_eff * z1x;
    out[3 * i + 1] = best * z2y + d_eff * z1y;
    out[3 * i + 2] = best * z2z + d_eff * z1z;
}

extern "C" void kernel_launch(void* const* d_in, const int* in_sizes, int n_in,
                              void* d_out, int out_size, void* d_ws, size_t ws_size,
                              hipStream_t stream) {
    const float* pos = (const float*)d_in[0];
    const float* nrm = (const float*)d_in[1];
    const float* dpt = (const float*)d_in[2];
    float* out = (float*)d_out;
    int N = in_sizes[0] / 3;
    int block = 256;
    int grid = (N + block - 1) / block;
    refract_kernel<<<grid, block, 0, stream>>>(pos, nrm, dpt, out, N);
}

// Round 4
// 32.368 us; speedup vs baseline: 2.0433x; 1.1302x over previous
//
#include <hip/hip_runtime.h>
#include <math.h>

// RefractiveInterface: per-ray Ferrari quartic solve replicating the JAX
// complex128 reference. Branch decisions (Dc / aa / bb signs) stay fp64;
// every expensive fp64 macro-op (sqrt, div, rsqrt, cbrt) is fp32-HW-seeded
// + one division-free fp64 Newton step (~1e-12, sufficient for fp32 roots
// and the 0.001 imag-classification window).

__device__ __forceinline__ double cbrt_fast(double x) {
    // cube root of x >= 0 via reciprocal-cbrt NR (division-free in fp64)
    if (x < 1e-30) return 0.0;                    // cbrt(1e-30)=1e-10 ~ 0
    double w = (double)(1.0f / cbrtf((float)x));  // seed ~1e-7 rel
    w = w * (4.0 - x * ((w * w) * w)) * (1.0 / 3.0);
    return x * (w * w);
}

__global__ __launch_bounds__(256) void refract_kernel(
    const float* __restrict__ pos,
    const float* __restrict__ nrm,
    const float* __restrict__ dpt,
    float* __restrict__ out,
    int N)
{
    int i = blockIdx.x * blockDim.x + threadIdx.x;
    if (i >= N) return;

    const float mu = 1.33f;
    float n0 = nrm[0], n1 = nrm[1];
    float d_eff = fmaxf(dpt[0], 0.0f) + 0.001f;   // relu(d)/1.0 + 0.001

    // ---- fp32 geometry ----
    float nn = sqrtf(n0 * n0 + n1 * n1 + 1.0f);
    float z1x = n0 / nn, z1y = n1 / nn, z1z = 1.0f / nn;

    float px = pos[3 * i + 0], py = pos[3 * i + 1], pz = pos[3 * i + 2];

    // cu = cross(z1, pos);  u = -||cu||  (identity: u = pos . z2 = -||z1 x pos||)
    float cux = z1y * pz - z1z * py;
    float cuy = z1z * px - z1x * pz;
    float cuz = z1x * py - z1y * px;
    float pn = sqrtf(cux * cux + cuy * cuy + cuz * cuz);
    float u = -pn;
    // z2 = cross(z1, cu) / pn
    float ipn = 1.0f / pn;
    float z2x = (z1y * cuz - z1z * cuy) * ipn;
    float z2y = (z1z * cux - z1x * cuz) * ipn;
    float z2z = (z1x * cuy - z1y * cux) * ipn;

    float v = px * z1x + py * z1y + pz * z1z;

    // quartic coefficients in fp32 (reference casts to f64 AFTER stacking)
    float c2f = -2.0f * u * (mu - 1.0f) * (mu + 1.0f);
    float c3f = d_eff * d_eff * mu * mu - d_eff * d_eff + 2.0f * d_eff * v
              + mu * mu * u * u - u * u - v * v;
    float c4f = -2.0f * d_eff * d_eff * mu * mu * u;
    float c5f = d_eff * d_eff * mu * mu * u * u;

    // ---- fp64 coefficient chain ----
    const double invc1 = 1.0 / (double)((1.33f - 1.0f) * (1.33f + 1.0f));
    double A0 = (double)c5f * invc1;
    double A1 = (double)c4f * invc1;
    double A2 = (double)c3f * invc1;
    double A3 = (double)c2f * invc1;

    double h = A3 * 0.25;
    double p = A2 - (6.0 * A3) * A3 * 0.0625;
    double q = A1 - A2 * A3 * 0.5 + 8.0 * ((h * h) * h);
    double r = A0 - A1 * A3 * 0.25 + ((A2 * A3) * A3) * 0.0625
             - 3.0 * ((h * h) * (h * h));

    double B2 = 2.0 * p;
    double B1 = p * p - 4.0 * r;
    double B0 = -(q * q);
    double pc  = B1 - B2 * B2 * (1.0 / 3.0);
    double qc  = B0 - B1 * B2 * (1.0 / 3.0) + ((B2 * B2) * B2) * (2.0 / 27.0);
    double hq  = qc * 0.5;
    double pc3 = pc * (1.0 / 3.0);
    double Dc  = hq * hq + (pc3 * pc3) * pc3 + 1e-12;
    double mql = -hq;
    double sh  = B2 * (1.0 / 3.0);

    double t;
    bool polish;

    if (Dc < 0.0) {
        // 3 genuine real roots: largest (trig form, fp32). |pc3| > 1e-4 here.
        float rr  = sqrtf((float)(-pc3));
        float rho = rr * rr * rr;
        float cphi = fminf(fmaxf((float)mql / rho, -1.0f), 1.0f);
        float yy = 2.0f * rr * cosf(acosf(cphi) * (1.0f / 3.0f));
        t = (double)yy - sh;
        polish = true;
    } else {
        // rcr = sqrt(Dc): fp32 rsqrt seed + one fp64 NR (division-free)
        double rcr;
        if (Dc < 1e-24) {
            rcr = 0.0;                          // sqrt <= 1e-12, negligible
        } else {
            double z = (double)rsqrtf((float)Dc);
            z = z * (1.5 - 0.5 * Dc * (z * z));
            rcr = Dc * z;
        }
        double aa = mql + rcr;
        double bb = mql - rcr;
        if (aa >= 0.0 && bb >= 0.0) {
            // genuine single real root: fp32 cbrt seeds + Halley polish
            t = (double)(cbrtf((float)aa) + cbrtf((float)bb)) - sh;
            polish = true;
        } else {
            // reference-junk replication (principal-branch Cardano)
            double ya = cbrt_fast(fabs(aa));
            double yb = cbrt_fast(fabs(bb));
            const double CI = 0.8660254037844386;  // sqrt(3)/2
            double Lre, Lim, Rre, Rim;
            if (aa >= 0.0) { Lre = ya;       Lim = 0.0;     }
            else           { Lre = 0.5 * ya; Lim = CI * ya; }
            if (bb >= 0.0) { Rre = yb;       Rim = 0.0;     }
            else           { Rre = 0.5 * yb; Rim = CI * yb; }
            const double o_re = -0.5, o_im = CI;
            const double o2_re = o_re * o_re - o_im * o_im;
            const double o2_im = 2.0 * o_re * o_im;
            double u0r = Lre + Rre - sh;
            double u0i = Lim + Rim;
            double u1r = (o2_re * Lre - o2_im * Lim) + (o_re * Rre - o_im * Rim) - sh;
            double u1i = (o2_re * Lim + o2_im * Lre) + (o_re * Rim + o_im * Rre);
            double u2r = (o_re * Lre - o_im * Lim) + (o2_re * Rre - o2_im * Rim) - sh;
            double u2i = (o_re * Lim + o_im * Lre) + (o2_re * Rim + o2_im * Rre);
            double cost0 = (u0r < 0.0) ? 1e6 : fabs(u0i);
            double cost1 = (u1r < 0.0) ? 1e6 : fabs(u1i);
            double cost2 = (u2r < 0.0) ? 1e6 : fabs(u2i);
            t = u0r; double cbv = cost0;
            if (cost1 < cbv) { cbv = cost1; t = u1r; }
            if (cost2 < cbv) { cbv = cost2; t = u2r; }
            polish = false;
        }
    }

    if (polish) {
        // one Halley step on f(t)=t^3+B2 t^2+B1 t+B0; fp32-rcp seed + fp64 NR
        double f   = ((t + B2) * t + B1) * t + B0;
        double fp  = (3.0 * t + 2.0 * B2) * t + B1;
        double fpp = 6.0 * t + 2.0 * B2;
        double den = fp * fp - 0.5 * f * fpp;
        double inv = (double)(1.0f / (float)den);
        inv = inv * (2.0 - den * inv);
        double dt  = (f * fp) * inv;
        if (isfinite(dt) && fabs(dt) < 0.1 * fabs(t) + 1e-2) t -= dt;
    }

    t = fmax(t, 1e-6);
    // rs = 1/sqrt(t): fp32 seed + one fp64 NR
    double rs = (double)rsqrtf((float)t);
    rs = rs * (1.5 - 0.5 * t * (rs * rs));
    double st = t * rs;
    double w  = (q * rs) * 0.5;    // == st*q/(2t)
    double pt2 = (p + t) * 0.5;
    double stst = st * st;
    double D1 = stst - 4.0 * (pt2 - w);
    double D2 = stst - 4.0 * (pt2 + w);

    // sqrt magnitudes in fp32; sign decisions in fp64. In any sign-flip
    // window |D|<1e-6 -> |imag|<5e-4 < 0.001 -> classification safe.
    float s1r = 0.0f, s1i = 0.0f, s2r = 0.0f, s2i = 0.0f;
    if (D1 >= 0.0) s1r = sqrtf((float)D1); else s1i = sqrtf((float)(-D1));
    if (D2 >= 0.0) s2r = sqrtf((float)D2); else s2i = sqrtf((float)(-D2));
    bool im1 = (s1i * 0.5f > 0.001f);
    bool im2 = (s2i * 0.5f > 0.001f);

    float stf = (float)st;
    float hf  = (float)h;
    float xr0 = (-stf + s1r) * 0.5f - hf;
    float xr1 = (-stf - s1r) * 0.5f - hf;
    float xr2 = ( stf + s2r) * 0.5f - hf;
    float xr3 = ( stf - s2r) * 0.5f - hf;

    // ---- fp32 error metric: e = |(u-x)*sqrt(mu^2 d^2 + (mu^2-1) x^2) - (v-d)x|
    // (uniform 1/mu factor dropped -- argmin invariant)
    float mm2 = mu * mu - 1.0f;           // > 0, sqrt arg always >= 0
    float mude2 = mu * mu * d_eff * d_eff;
    float vd = v - d_eff;
    float e0, e1, e2, e3;
    {
        float g;
        g = fmaf(mm2, xr0 * xr0, mude2);
        e0 = im1 ? INFINITY : fabsf((u - xr0) * sqrtf(g) - vd * xr0);
        g = fmaf(mm2, xr1 * xr1, mude2);
        e1 = im1 ? INFINITY : fabsf((u - xr1) * sqrtf(g) - vd * xr1);
        g = fmaf(mm2, xr2 * xr2, mude2);
        e2 = im2 ? INFINITY : fabsf((u - xr2) * sqrtf(g) - vd * xr2);
        g = fmaf(mm2, xr3 * xr3, mude2);
        e3 = im2 ? INFINITY : fabsf((u - xr3) * sqrtf(g) - vd * xr3);
    }
    float best = xr0; float eb = e0;
    if (e1 < eb) { eb = e1; best = xr1; }
    if (e2 < eb) { eb = e2; best = xr2; }
    if (e3 < eb) { eb = e3; best = xr3; }

    out[3 * i + 0] = best * z2x + d_eff * z1x;
    out[3 * i + 1] = best * z2y + d_eff * z1y;
    out[3 * i + 2] = best * z2z + d_eff * z1z;
}

extern "C" void kernel_launch(void* const* d_in, const int* in_sizes, int n_in,
                              void* d_out, int out_size, void* d_ws, size_t ws_size,
                              hipStream_t stream) {
    const float* pos = (const float*)d_in[0];
    const float* nrm = (const float*)d_in[1];
    const float* dpt = (const float*)d_in[2];
    float* out = (float*)d_out;
    int N = in_sizes[0] / 3;
    int block = 256;
    int grid = (N + block - 1) / block;
    refract_kernel<<<grid, block, 0, stream>>>(pos, nrm, dpt, out, N);
}

// Round 6
// 32.236 us; speedup vs baseline: 2.0517x; 1.0041x over previous
//
#include <hip/hip_runtime.h>
#include <math.h>

// RefractiveInterface: per-ray Ferrari quartic solve replicating the JAX
// complex128 reference. fp64 skeleton for all cancellation-sensitive values;
// all transcendentals are HW fp32 instructions (v_rcp/v_rsq/v_sqrt/v_exp/
// v_log) seeding division-free fp64 Newton steps. The Dc>=0 path (genuine +
// principal-branch-junk Cardano) is a single branchless sequence matching
// the reference's complex-arithmetic rounding structure.

__device__ __forceinline__ float fast_rcp(float x) { return __builtin_amdgcn_rcpf(x); }
__device__ __forceinline__ float fast_rsq(float x) { return __builtin_amdgcn_rsqf(x); }

// cube root of x >= 0, ~1e-15 rel: HW exp2/log2 seed of x^(-1/3), 2 fp64 NR.
__device__ __forceinline__ double cbrt2(double x) {
    float xf = (float)x;
    float wf = __builtin_amdgcn_exp2f(__builtin_amdgcn_logf(xf) * (-1.0f / 3.0f));
    double w = (double)wf;
    w = w * (4.0 - x * ((w * w) * w)) * (1.0 / 3.0);
    w = w * (4.0 - x * ((w * w) * w)) * (1.0 / 3.0);
    double c = x * (w * w);
    return (x < 1e-30) ? 0.0 : c;   // also kills NaN from w=inf seed
}

__global__ __launch_bounds__(256) void refract_kernel(
    const float* __restrict__ pos,
    const float* __restrict__ nrm,
    const float* __restrict__ dpt,
    float* __restrict__ out,
    int N)
{
    int i = blockIdx.x * blockDim.x + threadIdx.x;
    if (i >= N) return;

    const float mu = 1.33f;
    float n0 = nrm[0], n1 = nrm[1];
    float d_eff = fmaxf(dpt[0], 0.0f) + 0.001f;   // relu(d)/1.0 + 0.001

    // ---- fp32 geometry ----
    float nn = sqrtf(n0 * n0 + n1 * n1 + 1.0f);
    float z1x = n0 / nn, z1y = n1 / nn, z1z = 1.0f / nn;

    float px = pos[3 * i + 0], py = pos[3 * i + 1], pz = pos[3 * i + 2];

    // cu = cross(z1, pos);  u = -||cu||;  z2 = cross(z1, cu)/||cu||
    float cux = z1y * pz - z1z * py;
    float cuy = z1z * px - z1x * pz;
    float cuz = z1x * py - z1y * px;
    float pn = sqrtf(cux * cux + cuy * cuy + cuz * cuz);
    float u = -pn;
    float ipn = fast_rcp(pn);
    float z2x = (z1y * cuz - z1z * cuy) * ipn;
    float z2y = (z1z * cux - z1x * cuz) * ipn;
    float z2z = (z1x * cuy - z1y * cux) * ipn;

    float v = px * z1x + py * z1y + pz * z1z;

    // quartic coefficients in fp32 (reference casts to f64 AFTER stacking)
    float c2f = -2.0f * u * (mu - 1.0f) * (mu + 1.0f);
    float c3f = d_eff * d_eff * mu * mu - d_eff * d_eff + 2.0f * d_eff * v
              + mu * mu * u * u - u * u - v * v;
    float c4f = -2.0f * d_eff * d_eff * mu * mu * u;
    float c5f = d_eff * d_eff * mu * mu * u * u;

    // ---- fp64 coefficient chain ----
    const double invc1 = 1.0 / (double)((1.33f - 1.0f) * (1.33f + 1.0f));
    double A0 = (double)c5f * invc1;
    double A1 = (double)c4f * invc1;
    double A2 = (double)c3f * invc1;
    double A3 = (double)c2f * invc1;

    double h = A3 * 0.25;
    double p = A2 - (6.0 * A3) * A3 * 0.0625;
    double q = A1 - A2 * A3 * 0.5 + 8.0 * ((h * h) * h);
    double r = A0 - A1 * A3 * 0.25 + ((A2 * A3) * A3) * 0.0625
             - 3.0 * ((h * h) * (h * h));

    double B2 = 2.0 * p;
    double B1 = p * p - 4.0 * r;
    double B0 = -(q * q);
    double pc  = B1 - B2 * B2 * (1.0 / 3.0);
    double qc  = B0 - B1 * B2 * (1.0 / 3.0) + ((B2 * B2) * B2) * (2.0 / 27.0);
    double hq  = qc * 0.5;
    double pc3 = pc * (1.0 / 3.0);
    double Dc  = hq * hq + (pc3 * pc3) * pc3 + 1e-12;
    double mql = -hq;
    double sh  = B2 * (1.0 / 3.0);

    double t;
    bool polish;

    if (Dc < 0.0) {
        // 3 genuine real roots; reference's u0 = largest; any valid root is
        // factorization-equivalent. Solve 4T^3-3T = cphi, T=cos(acos/3):
        // monotone-from-above seed T0 = 0.5+sqrt((1+cphi)/6), 3 fp32 Newton,
        // then fp64 Halley (below) anchors to exact resolvent coefficients.
        float R2f = (float)(-pc3);            // > ~1e-4 when Dc<0
        float Rf  = sqrtf(R2f);
        float cphi = (float)mql * fast_rcp(R2f * Rf);
        cphi = fminf(fmaxf(cphi, -1.0f), 1.0f);
        float T = 0.5f + sqrtf((1.0f + cphi) * (1.0f / 6.0f));
        #pragma unroll
        for (int k = 0; k < 3; ++k) {
            float g  = fmaf(fmaf(4.0f * T, T, -3.0f), T, -cphi);
            float gp = fmaf(12.0f * T, T, -3.0f);
            T -= g * fast_rcp(gp + 1e-12f);   // eps: exact double-root case
        }
        t = (double)(2.0f * Rf * T) - sh;
        polish = true;
    } else {
        // rcr = sqrt(Dc): fp32 rsq seed + one fp64 NR
        double rcr;
        if (Dc < 1e-36) {
            rcr = 0.0;
        } else {
            double z = (double)fast_rsq((float)Dc);
            z = z * (1.5 - 0.5 * Dc * (z * z));
            rcr = Dc * z;
        }
        double aa = mql + rcr;
        double bb = mql - rcr;
        bool na = (aa < 0.0), nb = (bb < 0.0);
        double ca = cbrt2(fabs(aa));
        double cb = cbrt2(fabs(bb));

        // principal-branch cube roots: negative arg -> rotate by cis(pi/3)
        const double CI = 0.8660254037844386;   // sqrt(3)/2
        double Lre = na ? 0.5 * ca : ca;
        double Lim = na ? CI * ca  : 0.0;
        double Rre = nb ? 0.5 * cb : cb;
        double Rim = nb ? CI * cb  : 0.0;

        // omega combos, o=(-0.5,CI), o^2=(-0.5,-CI) exactly (ref rounding)
        double u0r = (Lre + Rre) - sh;
        double u0i =  Lim + Rim;
        double u1r = (-0.5 * Lre + CI * Lim) + (-0.5 * Rre - CI * Rim) - sh;
        double u1i = (-0.5 * Lim - CI * Lre) + (-0.5 * Rim + CI * Rre);
        double u2r = (-0.5 * Lre - CI * Lim) + (-0.5 * Rre + CI * Rim) - sh;
        double u2i = (-0.5 * Lim + CI * Lre) + (-0.5 * Rim - CI * Rre);

        // cost = where(real<0, 1e6, |imag|); first-occurrence argmin
        double c0 = (u0r < 0.0) ? 1e6 : fabs(u0i);
        double c1 = (u1r < 0.0) ? 1e6 : fabs(u1i);
        double c2 = (u2r < 0.0) ? 1e6 : fabs(u2i);
        int bi = 0; double cbest = c0; t = u0r;
        if (c1 < cbest) { cbest = c1; t = u1r; bi = 1; }
        if (c2 < cbest) { cbest = c2; t = u2r; bi = 2; }
        polish = (!na && !nb && bi == 0);   // genuine single real root
    }

    if (polish) {
        // one Halley step on f(t)=t^3+B2 t^2+B1 t+B0; rcp seed + fp64 NR
        double f   = ((t + B2) * t + B1) * t + B0;
        double fp  = (3.0 * t + 2.0 * B2) * t + B1;
        double fpp = 6.0 * t + 2.0 * B2;
        double den = fp * fp - 0.5 * f * fpp;
        double inv = (double)fast_rcp((float)den);
        inv = inv * (2.0 - den * inv);
        double dt  = (f * fp) * inv;
        if (isfinite(dt) && fabs(dt) < 0.1 * fabs(t) + 1e-2) t -= dt;
    }

    t = fmax(t, 1e-6);
    // rs = 1/sqrt(t): fp32 HW seed + one fp64 NR
    double rs = (double)fast_rsq((float)t);
    rs = rs * (1.5 - 0.5 * t * (rs * rs));
    double st = t * rs;
    double w  = (q * rs) * 0.5;    // == st*q/(2t)
    double pt2 = (p + t) * 0.5;
    double stst = st * st;
    double D1 = stst - 4.0 * (pt2 - w);
    double D2 = stst - 4.0 * (pt2 + w);

    // sqrt magnitudes fp32; sign decisions fp64. Any sign-flip window has
    // |D|<1e-6 -> |imag|<5e-4 < 0.001 -> classification safe.
    float s1r = 0.0f, s1i = 0.0f, s2r = 0.0f, s2i = 0.0f;
    if (D1 >= 0.0) s1r = sqrtf((float)D1); else s1i = sqrtf((float)(-D1));
    if (D2 >= 0.0) s2r = sqrtf((float)D2); else s2i = sqrtf((float)(-D2));
    bool im1 = (s1i * 0.5f > 0.001f);
    bool im2 = (s2i * 0.5f > 0.001f);

    float stf = (float)st;
    float hf  = (float)h;
    float xr0 = (-stf + s1r) * 0.5f - hf;
    float xr1 = (-stf - s1r) * 0.5f - hf;
    float xr2 = ( stf + s2r) * 0.5f - hf;
    float xr3 = ( stf - s2r) * 0.5f - hf;

    // ---- fp32 error metric: e = |(u-x)*sqrt(mu^2 d^2 + (mu^2-1) x^2) - (v-d)x|
    float mm2 = mu * mu - 1.0f;
    float mude2 = mu * mu * d_eff * d_eff;
    float vd = v - d_eff;
    float g0 = fmaf(mm2, xr0 * xr0, mude2);
    float g1 = fmaf(mm2, xr1 * xr1, mude2);
    float g2 = fmaf(mm2, xr2 * xr2, mude2);
    float g3 = fmaf(mm2, xr3 * xr3, mude2);
    float e0 = im1 ? INFINITY : fabsf((u - xr0) * sqrtf(g0) - vd * xr0);
    float e1 = im1 ? INFINITY : fabsf((u - xr1) * sqrtf(g1) - vd * xr1);
    float e2 = im2 ? INFINITY : fabsf((u - xr2) * sqrtf(g2) - vd * xr2);
    float e3 = im2 ? INFINITY : fabsf((u - xr3) * sqrtf(g3) - vd * xr3);

    float best = xr0; float eb = e0;
    if (e1 < eb) { eb = e1; best = xr1; }
    if (e2 < eb) { eb = e2; best = xr2; }
    if (e3 < eb) { eb = e3; best = xr3; }

    out[3 * i + 0] = best * z2x + d_eff * z1x;
    out[3 * i + 1] = best * z2y + d_eff * z1y;
    out[3 * i + 2] = best * z2z + d_eff * z1z;
}

extern "C" void kernel_launch(void* const* d_in, const int* in_sizes, int n_in,
                              void* d_out, int out_size, void* d_ws, size_t ws_size,
                              hipStream_t stream) {
    const float* pos = (const float*)d_in[0];
    const float* nrm = (const float*)d_in[1];
    const float* dpt = (const float*)d_in[2];
    float* out = (float*)d_out;
    int N = in_sizes[0] / 3;
    int block = 256;
    int grid = (N + block - 1) / block;
    refract_kernel<<<grid, block, 0, stream>>>(pos, nrm, dpt, out, N);
}

// Round 7
// 30.306 us; speedup vs baseline: 2.1823x; 1.0637x over previous
//
#include <hip/hip_runtime.h>
#include <math.h>

// RefractiveInterface: per-ray Ferrari quartic solve replicating the JAX
// complex128 reference. fp64 skeleton for cancellation-sensitive values;
// HW fp32 seeds + division-free fp64 NR for all macro-ops. Case-specialized:
//   Dc<0   : fp32 trig-Newton seed + one fp64 Halley (in-branch).
//   Dc>=0 genuine (both cbrt args >= 0): closed-form selection, no omega
//            combos, no polish (1-NR cbrt is ~1e-14 rel already).
//   Dc>=0 junk (principal-branch Cardano fabrication): exact replication.

__device__ __forceinline__ float fast_rcp(float x) { return __builtin_amdgcn_rcpf(x); }
__device__ __forceinline__ float fast_rsq(float x) { return __builtin_amdgcn_rsqf(x); }

// cube root of x >= 0, ~1e-14 rel: HW exp2/log2 seed of x^(-1/3), 1 fp64 NR.
__device__ __forceinline__ double cbrt1(double x) {
    float xf = (float)x;
    float wf = __builtin_amdgcn_exp2f(__builtin_amdgcn_logf(xf) * (-1.0f / 3.0f));
    double w = (double)wf;
    w = w * (4.0 - x * ((w * w) * w)) * (1.0 / 3.0);
    double c = x * (w * w);
    return (x < 1e-30) ? 0.0 : c;   // also kills NaN from w=inf seed
}

__global__ __launch_bounds__(256) void refract_kernel(
    const float* __restrict__ pos,
    const float* __restrict__ nrm,
    const float* __restrict__ dpt,
    float* __restrict__ out,
    int N)
{
    int i = blockIdx.x * blockDim.x + threadIdx.x;
    if (i >= N) return;

    const float mu = 1.33f;
    float n0 = nrm[0], n1 = nrm[1];
    float d_eff = fmaxf(dpt[0], 0.0f) + 0.001f;   // relu(d)/1.0 + 0.001

    // ---- fp32 geometry ----
    float nn = sqrtf(n0 * n0 + n1 * n1 + 1.0f);
    float z1x = n0 / nn, z1y = n1 / nn, z1z = 1.0f / nn;

    float px = pos[3 * i + 0], py = pos[3 * i + 1], pz = pos[3 * i + 2];

    // cu = cross(z1, pos);  u = -||cu||;  z2 = cross(z1, cu)/||cu||
    float cux = z1y * pz - z1z * py;
    float cuy = z1z * px - z1x * pz;
    float cuz = z1x * py - z1y * px;
    float pn = sqrtf(cux * cux + cuy * cuy + cuz * cuz);
    float u = -pn;
    float ipn = fast_rcp(pn);
    float z2x = (z1y * cuz - z1z * cuy) * ipn;
    float z2y = (z1z * cux - z1x * cuz) * ipn;
    float z2z = (z1x * cuy - z1y * cux) * ipn;

    float v = px * z1x + py * z1y + pz * z1z;

    // quartic coefficients in fp32 (reference casts to f64 AFTER stacking)
    float c2f = -2.0f * u * (mu - 1.0f) * (mu + 1.0f);
    float c3f = d_eff * d_eff * mu * mu - d_eff * d_eff + 2.0f * d_eff * v
              + mu * mu * u * u - u * u - v * v;
    float c4f = -2.0f * d_eff * d_eff * mu * mu * u;
    float c5f = d_eff * d_eff * mu * mu * u * u;

    // ---- fp64 coefficient chain ----
    const double invc1 = 1.0 / (double)((1.33f - 1.0f) * (1.33f + 1.0f));
    double A0 = (double)c5f * invc1;
    double A1 = (double)c4f * invc1;
    double A2 = (double)c3f * invc1;
    double A3 = (double)c2f * invc1;

    double h = A3 * 0.25;
    double p = A2 - (6.0 * A3) * A3 * 0.0625;
    double q = A1 - A2 * A3 * 0.5 + 8.0 * ((h * h) * h);
    double r = A0 - A1 * A3 * 0.25 + ((A2 * A3) * A3) * 0.0625
             - 3.0 * ((h * h) * (h * h));

    double B2 = 2.0 * p;
    double B1 = p * p - 4.0 * r;
    double B0 = -(q * q);
    double pc  = B1 - B2 * B2 * (1.0 / 3.0);
    double qc  = B0 - B1 * B2 * (1.0 / 3.0) + ((B2 * B2) * B2) * (2.0 / 27.0);
    double hq  = qc * 0.5;
    double pc3 = pc * (1.0 / 3.0);
    double Dc  = hq * hq + (pc3 * pc3) * pc3 + 1e-12;
    double mql = -hq;
    double sh  = B2 * (1.0 / 3.0);

    double t;

    if (Dc < 0.0) {
        // 3 genuine real roots; largest. Solve 4T^3-3T = cphi (T=cos(acos/3)):
        // monotone-from-above seed, 3 fp32 Newton, then one fp64 Halley
        // anchors to the exact resolvent coefficients.
        float R2f = (float)(-pc3);            // > ~1e-4 when Dc<0
        float Rf  = sqrtf(R2f);
        float cphi = (float)mql * fast_rcp(R2f * Rf);
        cphi = fminf(fmaxf(cphi, -1.0f), 1.0f);
        float T = 0.5f + sqrtf((1.0f + cphi) * (1.0f / 6.0f));
        #pragma unroll
        for (int k = 0; k < 3; ++k) {
            float g  = fmaf(fmaf(4.0f * T, T, -3.0f), T, -cphi);
            float gp = fmaf(12.0f * T, T, -3.0f);
            T -= g * fast_rcp(gp + 1e-12f);   // eps: exact double-root case
        }
        t = (double)(2.0f * Rf * T) - sh;

        // one Halley step on f(t)=t^3+B2 t^2+B1 t+B0 (seed ~1e-6 rel)
        double f   = ((t + B2) * t + B1) * t + B0;
        double fp  = (3.0 * t + 2.0 * B2) * t + B1;
        double fpp = 6.0 * t + 2.0 * B2;
        double den = fp * fp - 0.5 * f * fpp;
        double inv = (double)fast_rcp((float)den);
        inv = inv * (2.0 - den * inv);
        double dt  = (f * fp) * inv;
        if (isfinite(dt) && fabs(dt) < 0.1 * fabs(t) + 1e-2) t -= dt;
    } else {
        // rcr = sqrt(Dc): fp32 rsq seed + one fp64 NR
        double rcr;
        if (Dc < 1e-36) {
            rcr = 0.0;
        } else {
            double z = (double)fast_rsq((float)Dc);
            z = z * (1.5 - 0.5 * Dc * (z * z));
            rcr = Dc * z;
        }
        double aa = mql + rcr;
        double bb = mql - rcr;
        bool na = (aa < 0.0), nb = (bb < 0.0);
        double ca = cbrt1(fabs(aa));
        double cb = cbrt1(fabs(bb));

        if (!na && !nb) {
            // genuine: u0 = ca+cb-sh has imag exactly 0 -> cost0 = 0 -> picked
            // when u0r>=0. Else conj pair: cost1==cost2 bitwise -> u1 first;
            // u1r = -0.5*(ca+cb)-sh (scale-invariant rounding == ref's form).
            double s = ca + cb;
            double u0r = s - sh;
            t = (u0r >= 0.0) ? u0r : (-0.5 * s - sh);
        } else {
            // reference-junk replication (principal-branch Cardano):
            // negative arg -> rotate cube root by cis(pi/3)
            const double CI = 0.8660254037844386;   // sqrt(3)/2
            double Lre = na ? 0.5 * ca : ca;
            double Lim = na ? CI * ca  : 0.0;
            double Rre = nb ? 0.5 * cb : cb;
            double Rim = nb ? CI * cb  : 0.0;

            double u0r = (Lre + Rre) - sh;
            double u0i =  Lim + Rim;
            double u1r = (-0.5 * Lre + CI * Lim) + (-0.5 * Rre - CI * Rim) - sh;
            double u1i = (-0.5 * Lim - CI * Lre) + (-0.5 * Rim + CI * Rre);
            double u2r = (-0.5 * Lre - CI * Lim) + (-0.5 * Rre + CI * Rim) - sh;
            double u2i = (-0.5 * Lim + CI * Lre) + (-0.5 * Rim - CI * Rre);

            double c0 = (u0r < 0.0) ? 1e6 : fabs(u0i);
            double c1 = (u1r < 0.0) ? 1e6 : fabs(u1i);
            double c2 = (u2r < 0.0) ? 1e6 : fabs(u2i);
            double cbest = c0; t = u0r;
            if (c1 < cbest) { cbest = c1; t = u1r; }
            if (c2 < cbest) { t = u2r; }
        }
    }

    t = fmax(t, 1e-6);
    // rs = 1/sqrt(t): fp32 HW seed + one fp64 NR
    double rs = (double)fast_rsq((float)t);
    rs = rs * (1.5 - 0.5 * t * (rs * rs));
    double st = t * rs;
    double w  = (q * rs) * 0.5;    // == st*q/(2t)
    double pt2 = (p + t) * 0.5;
    double stst = st * st;
    double D1 = stst - 4.0 * (pt2 - w);
    double D2 = stst - 4.0 * (pt2 + w);

    // sqrt magnitudes fp32; sign decisions fp64. Any sign-flip window has
    // |D|<1e-6 -> |imag|<5e-4 < 0.001 -> classification safe.
    float s1r = 0.0f, s1i = 0.0f, s2r = 0.0f, s2i = 0.0f;
    if (D1 >= 0.0) s1r = sqrtf((float)D1); else s1i = sqrtf((float)(-D1));
    if (D2 >= 0.0) s2r = sqrtf((float)D2); else s2i = sqrtf((float)(-D2));
    bool im1 = (s1i * 0.5f > 0.001f);
    bool im2 = (s2i * 0.5f > 0.001f);

    float stf = (float)st;
    float hf  = (float)h;
    float xr0 = (-stf + s1r) * 0.5f - hf;
    float xr1 = (-stf - s1r) * 0.5f - hf;
    float xr2 = ( stf + s2r) * 0.5f - hf;
    float xr3 = ( stf - s2r) * 0.5f - hf;

    // ---- fp32 error metric: e = |(u-x)*sqrt(mu^2 d^2 + (mu^2-1) x^2) - (v-d)x|
    float mm2 = mu * mu - 1.0f;
    float mude2 = mu * mu * d_eff * d_eff;
    float vd = v - d_eff;
    float g0 = fmaf(mm2, xr0 * xr0, mude2);
    float g1 = fmaf(mm2, xr1 * xr1, mude2);
    float g2 = fmaf(mm2, xr2 * xr2, mude2);
    float g3 = fmaf(mm2, xr3 * xr3, mude2);
    float e0 = im1 ? INFINITY : fabsf((u - xr0) * sqrtf(g0) - vd * xr0);
    float e1 = im1 ? INFINITY : fabsf((u - xr1) * sqrtf(g1) - vd * xr1);
    float e2 = im2 ? INFINITY : fabsf((u - xr2) * sqrtf(g2) - vd * xr2);
    float e3 = im2 ? INFINITY : fabsf((u - xr3) * sqrtf(g3) - vd * xr3);

    float best = xr0; float eb = e0;
    if (e1 < eb) { eb = e1; best = xr1; }
    if (e2 < eb) { eb = e2; best = xr2; }
    if (e3 < eb) { eb = e3; best = xr3; }

    out[3 * i + 0] = best * z2x + d_eff * z1x;
    out[3 * i + 1] = best * z2y + d_eff * z1y;
    out[3 * i + 2] = best * z2z + d_eff * z1z;
}

extern "C" void kernel_launch(void* const* d_in, const int* in_sizes, int n_in,
                              void* d_out, int out_size, void* d_ws, size_t ws_size,
                              hipStream_t stream) {
    const float* pos = (const float*)d_in[0];
    const float* nrm = (const float*)d_in[1];
    const float* dpt = (const float*)d_in[2];
    float* out = (float*)d_out;
    int N = in_sizes[0] / 3;
    int block = 256;
    int grid = (N + block - 1) / block;
    refract_kernel<<<grid, block, 0, stream>>>(pos, nrm, dpt, out, N);
}

// Round 9
// 29.000 us; speedup vs baseline: 2.2806x; 1.0451x over previous
//
#include <hip/hip_runtime.h>
#include <math.h>

// RefractiveInterface: per-ray Ferrari quartic solve. Consistent-quartic
// principle: the reference's coefficients carry fp32 noise (rel ~1e-7), so
// any algebraically-equivalent coefficient chain within that noise class is
// output-equivalent; we need ~1e-12 accuracy on OUR quartic, not the
// reference's bitwise rounding. Structure exploited: A3=-2u, A0=-A1*u/2 =>
// collapsed p/q/r; aa*bb = -pc3^3 => single cbrt; st^2=t => fused D1/D2
// (D1 = 2*q*rs - (t+2p), D2 = -2*q*rs - (t+2p) -- factor 2 verified).

__device__ __forceinline__ float fast_rcp(float x) { return __builtin_amdgcn_rcpf(x); }
__device__ __forceinline__ float fast_rsq(float x) { return __builtin_amdgcn_rsqf(x); }

// cube root of x>=0: returns c = x^(1/3), w = x^(-1/3) (~1e-14 rel).
// HW exp2/log2 fp32 seed + 1 fp64 NR on w. x<1e-30 -> (0,0) (w=0 so that
// identity-derived partners come out 0 instead of inf/NaN).
__device__ __forceinline__ void cbrt_cw(double x, double& c, double& w) {
    float xf = (float)x;
    float wf = __builtin_amdgcn_exp2f(__builtin_amdgcn_logf(xf) * (-1.0f / 3.0f));
    double wd = (double)wf;
    wd = wd * (4.0 - x * ((wd * wd) * wd)) * (1.0 / 3.0);
    bool tiny = (x < 1e-30);
    w = tiny ? 0.0 : wd;
    c = tiny ? 0.0 : x * (wd * wd);
}

__global__ __launch_bounds__(256) void refract_kernel(
    const float* __restrict__ pos,
    const float* __restrict__ nrm,
    const float* __restrict__ dpt,
    float* __restrict__ out,
    int N)
{
    int i = blockIdx.x * blockDim.x + threadIdx.x;
    if (i >= N) return;

    const float mu = 1.33f;
    float n0 = nrm[0], n1 = nrm[1];
    float d_eff = fmaxf(dpt[0], 0.0f) + 0.001f;   // relu(d)/1.0 + 0.001

    // ---- fp32 geometry ----
    float nn = sqrtf(n0 * n0 + n1 * n1 + 1.0f);
    float z1x = n0 / nn, z1y = n1 / nn, z1z = 1.0f / nn;

    float px = pos[3 * i + 0], py = pos[3 * i + 1], pz = pos[3 * i + 2];

    // cu = cross(z1, pos);  u = -||cu||;  z2 = cross(z1, cu)/||cu||
    float cux = z1y * pz - z1z * py;
    float cuy = z1z * px - z1x * pz;
    float cuz = z1x * py - z1y * px;
    float pn = sqrtf(cux * cux + cuy * cuy + cuz * cuz);
    float u = -pn;
    float ipn = fast_rcp(pn);
    float z2x = (z1y * cuz - z1z * cuy) * ipn;
    float z2y = (z1z * cux - z1x * cuz) * ipn;
    float z2z = (z1x * cuy - z1y * cux) * ipn;

    float v = px * z1x + py * z1y + pz * z1z;

    // c3 in fp32 (mirrors reference's noisiest coefficient), rest closed-form
    float c3f = d_eff * d_eff * mu * mu - d_eff * d_eff + 2.0f * d_eff * v
              + mu * mu * u * u - u * u - v * v;

    // ---- fp64 collapsed coefficient chain ----
    // monic quartic: x^4 - 2u x^3 + G x^2 + km*u x + (-km*u/2)*u  (G=c3/K)
    const double invc1 = 1.0 / (double)((1.33f - 1.0f) * (1.33f + 1.0f));
    const double mu2d = (double)(1.33f) * (double)(1.33f);
    double dm = (double)d_eff;
    double km = -2.0 * dm * dm * mu2d * invc1;    // A1/u

    double ud = (double)u;
    double G  = (double)c3f * invc1;
    double U  = ud * ud;
    double p  = fma(-1.5, U, G);
    double q  = ud * ((G - U) + km);
    double r  = 0.25 * U * fma(-0.75, U, G);
    double p2 = p * p;
    double q2 = q * q;
    double pr = p * r;
    double p3 = p2 * p;
    // depressed resolvent: mql = -qc/2, pc3 = pc/3
    double mql = fma(p3, 1.0 / 27.0, fma(pr, -4.0 / 3.0, 0.5 * q2));
    double pc3 = fma(p2, -1.0 / 9.0, (-4.0 / 3.0) * r);
    double Dc  = fma(pc3 * pc3, pc3, fma(mql, mql, 1e-12));
    double sh  = p * (2.0 / 3.0);
    double p2d = p + p;

    double t;

    if (Dc < 0.0) {
        // 3 genuine real roots; largest. 4T^3-3T = cphi, T = cos(acos/3):
        // monotone-from-above seed, 3 fp32 Newton, one fp64 Halley anchor.
        float R2f = (float)(-pc3);
        float Rf  = sqrtf(R2f);
        float cphi = (float)mql * fast_rcp(R2f * Rf);
        cphi = fminf(fmaxf(cphi, -1.0f), 1.0f);
        float T = 0.5f + sqrtf((1.0f + cphi) * (1.0f / 6.0f));
        #pragma unroll
        for (int k = 0; k < 3; ++k) {
            float g  = fmaf(fmaf(4.0f * T, T, -3.0f), T, -cphi);
            float gp = fmaf(12.0f * T, T, -3.0f);
            T -= g * fast_rcp(gp + 1e-12f);
        }
        t = (double)(2.0f * Rf * T) - sh;

        // Halley on f(t) = ((t+2p)t + (p^2-4r))t - q^2
        double B1n = fma(-4.0, r, p2);
        double f   = ((t + p2d) * t + B1n) * t - q2;
        double fp  = fma(3.0 * t + p2d, t, (t * p2d + B1n));  // 3t^2+4pt+B1n
        double fpp = 6.0 * t + 2.0 * p2d;
        double den = fp * fp - 0.5 * f * fpp;
        double inv = (double)fast_rcp((float)den);
        inv = inv * (2.0 - den * inv);
        double dt  = (f * fp) * inv;
        if (isfinite(dt) && fabs(dt) < 0.1 * fabs(t) + 1e-2) t -= dt;
    } else {
        // rcr = sqrt(Dc): fp32 rsq seed + one fp64 NR
        double rcr;
        if (Dc < 1e-36) {
            rcr = 0.0;
        } else {
            double z = (double)fast_rsq((float)Dc);
            z = z * (1.5 - 0.5 * Dc * (z * z));
            rcr = Dc * z;
        }
        double aa = mql + rcr;
        double bb = mql - rcr;
        bool na = (aa < 0.0), nb = (bb < 0.0);

        // single cbrt: |aa|*|bb| = |pc3|^3 -> cbrt the larger, derive smaller
        double absa = fabs(aa), absb = fabs(bb);
        bool aBig = (absa >= absb);
        double big = aBig ? absa : absb;
        double cbig, wbig;
        cbrt_cw(big, cbig, wbig);
        double csml = fabs(pc3) * wbig;
        double ca = aBig ? cbig : csml;
        double cb = aBig ? csml : cbig;

        if (!na && !nb) {
            // genuine: u0 = ca+cb-sh (imag 0, cost 0) when u0r>=0; else the
            // conjugate pair ties -> first (u1), u1r = -0.5(ca+cb)-sh.
            double s = ca + cb;
            double u0r = s - sh;
            t = (u0r >= 0.0) ? u0r : fma(-0.5, s, -sh);
        } else {
            // principal-branch Cardano junk replication:
            // negative arg -> cube root rotated by cis(pi/3)
            const double CI = 0.8660254037844386;   // sqrt(3)/2
            double Lre = na ? 0.5 * ca : ca;
            double Lim = na ? CI * ca  : 0.0;
            double Rre = nb ? 0.5 * cb : cb;
            double Rim = nb ? CI * cb  : 0.0;

            double u0r = (Lre + Rre) - sh;
            double u0i =  Lim + Rim;
            double u1r = (-0.5 * Lre + CI * Lim) + (-0.5 * Rre - CI * Rim) - sh;
            double u1i = (-0.5 * Lim - CI * Lre) + (-0.5 * Rim + CI * Rre);
            double u2r = (-0.5 * Lre - CI * Lim) + (-0.5 * Rre + CI * Rim) - sh;
            double u2i = (-0.5 * Lim + CI * Lre) + (-0.5 * Rim - CI * Rre);

            double c0 = (u0r < 0.0) ? 1e6 : fabs(u0i);
            double c1 = (u1r < 0.0) ? 1e6 : fabs(u1i);
            double c2 = (u2r < 0.0) ? 1e6 : fabs(u2i);
            double cbest = c0; t = u0r;
            if (c1 < cbest) { cbest = c1; t = u1r; }
            if (c2 < cbest) { t = u2r; }
        }
    }

    t = fmax(t, 1e-6);
    // rs = 1/sqrt(t): fp32 HW seed + one fp64 NR
    double rs = (double)fast_rsq((float)t);
    rs = rs * (1.5 - 0.5 * t * (rs * rs));
    double st = t * rs;
    // st^2 = t (1e-13): D1 = 2*q*rs - (t+2p), D2 = -2*q*rs - (t+2p)
    double tp = t + p2d;
    double wq = 2.0 * (q * rs);
    double D1 = wq - tp;
    double D2 = -wq - tp;

    // sqrt magnitudes fp32; sign decisions fp64. Sign-flip window |D|<1e-6
    // -> |imag|<5e-4 < 0.001 -> classification safe.
    float s1r = 0.0f, s1i = 0.0f, s2r = 0.0f, s2i = 0.0f;
    if (D1 >= 0.0) s1r = sqrtf((float)D1); else s1i = sqrtf((float)(-D1));
    if (D2 >= 0.0) s2r = sqrtf((float)D2); else s2i = sqrtf((float)(-D2));
    bool im1 = (s1i * 0.5f > 0.001f);
    bool im2 = (s2i * 0.5f > 0.001f);

    float stf = (float)st;
    float uh  = 0.5f * u;                 // -h in fp32 (h = -u/2)
    float xr0 = (-stf + s1r) * 0.5f + uh;
    float xr1 = (-stf - s1r) * 0.5f + uh;
    float xr2 = ( stf + s2r) * 0.5f + uh;
    float xr3 = ( stf - s2r) * 0.5f + uh;

    // ---- fp32 error metric: e = |(u-x)*sqrt(mu^2 d^2 + (mu^2-1) x^2) - (v-d)x|
    float mm2 = mu * mu - 1.0f;
    float mude2 = mu * mu * d_eff * d_eff;
    float vd = v - d_eff;
    float g0 = fmaf(mm2, xr0 * xr0, mude2);
    float g1 = fmaf(mm2, xr1 * xr1, mude2);
    float g2 = fmaf(mm2, xr2 * xr2, mude2);
    float g3 = fmaf(mm2, xr3 * xr3, mude2);
    float e0 = im1 ? INFINITY : fabsf((u - xr0) * sqrtf(g0) - vd * xr0);
    float e1 = im1 ? INFINITY : fabsf((u - xr1) * sqrtf(g1) - vd * xr1);
    float e2 = im2 ? INFINITY : fabsf((u - xr2) * sqrtf(g2) - vd * xr2);
    float e3 = im2 ? INFINITY : fabsf((u - xr3) * sqrtf(g3) - vd * xr3);

    float best = xr0; float eb = e0;
    if (e1 < eb) { eb = e1; best = xr1; }
    if (e2 < eb) { eb = e2; best = xr2; }
    if (e3 < eb) { eb = e3; best = xr3; }

    out[3 * i + 0] = best * z2x + d_eff * z1x;
    out[3 * i + 1] = best * z2y + d_eff * z1y;
    out[3 * i + 2] = best * z2z + d_eff * z1z;
}

extern "C" void kernel_launch(void* const* d_in, const int* in_sizes, int n_in,
                              void* d_out, int out_size, void* d_ws, size_t ws_size,
                              hipStream_t stream) {
    const float* pos = (const float*)d_in[0];
    const float* nrm = (const float*)d_in[1];
    const float* dpt = (const float*)d_in[2];
    float* out = (float*)d_out;
    int N = in_sizes[0] / 3;
    int block = 256;
    int grid = (N + block - 1) / block;
    refract_kernel<<<grid, block, 0, stream>>>(pos, nrm, dpt, out, N);
}